// Round 6
// baseline (328.174 us; speedup 1.0000x reference)
//
#include <hip/hip_runtime.h>
#include <hip/hip_cooperative_groups.h>
#include <math.h>

namespace cg = cooperative_groups;

#define D      4096
#define NPREV  8191
#define NROWS  8192
#define NB     256          // blocks (1 per CU, grid-resident)
#define NT     1024         // threads per block (16 waves)
#define RPB    (NROWS / NB) // 32 rows per block in flash phase
#define BATCH  16           // rows held in registers at once

typedef float f4 __attribute__((ext_vector_type(4)));

static __device__ __forceinline__ f4 nt_load4(const float* p) {
    return __builtin_nontemporal_load(reinterpret_cast<const f4*>(p));
}
static __device__ __forceinline__ void nt_store4(f4 v, float* p) {
    __builtin_nontemporal_store(v, reinterpret_cast<f4*>(p));
}
static __device__ __forceinline__ f4 ld4(const float* p) {
    return *reinterpret_cast<const f4*>(p);
}
static __device__ __forceinline__ void st4(f4 v, float* p) {
    *reinterpret_cast<f4*>(p) = v;
}

// ============ P1 / P5: out[row] = dot(W[row,:], v) (+resid), wave per row ====
static __device__ __forceinline__ void phase_matvec(
        const float* __restrict__ W, const float* __restrict__ v,
        const float* __restrict__ resid, float* __restrict__ out,
        int bid, int tid) {
    int row  = bid * (NT / 64) + (tid >> 6);   // 256*16 = 4096 waves = D rows
    int lane = tid & 63;
    const float* Wrow = W + (size_t)row * D;
    float acc = 0.f;
    #pragma unroll
    for (int i = 0; i < 16; ++i) {
        int c = lane + i * 64;
        f4 w = nt_load4(Wrow + 4 * c);
        f4 x = ld4(v + 4 * c);
        acc += w.x * x.x + w.y * x.y + w.z * x.z + w.w * x.w;
    }
    #pragma unroll
    for (int off = 32; off; off >>= 1) acc += __shfl_down(acc, off, 64);
    if (lane == 0) out[row] = resid ? (acc + resid[row]) : acc;
}

// ============ P2a: kqpart[b][d] = sum over 16 rows of q[m]*W_K[m][d] =========
static __device__ __forceinline__ void phase_colpart(
        const float* __restrict__ W, const float* __restrict__ q,
        float* __restrict__ kqpart, int bid, int tid, float* s_q) {
    int m0 = bid * 16;
    if (tid < 16) s_q[tid] = q[m0 + tid];
    __syncthreads();
    f4 acc = (f4)0.f;
    #pragma unroll
    for (int r = 0; r < 16; ++r)
        acc += s_q[r] * nt_load4(W + (size_t)(m0 + r) * D + 4 * tid);
    st4(acc, kqpart + (size_t)bid * D + 4 * tid);
}

// ============ P2b: kq[d] = sum_b kqpart[b][d] ================================
static __device__ __forceinline__ void phase_colreduce(
        const float* __restrict__ kqpart, float* __restrict__ kq,
        int bid, int tid) {
    int col  = bid * 16 + (tid >> 6);          // 256*16 = 4096 columns
    int lane = tid & 63;
    float s = 0.f;
    #pragma unroll
    for (int i = 0; i < 4; ++i)
        s += kqpart[(size_t)(lane + 64 * i) * D + col];
    #pragma unroll
    for (int off = 32; off; off >>= 1) s += __shfl_down(s, off, 64);
    if (lane == 0) kq[col] = s;
}

// ============ P3: flash — copy rows to io, logits, online softmax, ctx part ==
static __device__ __forceinline__ void phase_flash(
        const float* __restrict__ prev, const float* __restrict__ inp,
        const float* __restrict__ kq, float* __restrict__ io,
        float* __restrict__ ms, float* __restrict__ ctxpart,
        int bid, int tid, float* s_wred /*256*/, float* s_log /*16*/) {
    const int n0 = bid * RPB;
    const int wid = tid >> 6, lane = tid & 63;
    const f4 kqv = ld4(kq + 4 * tid);
    float run_m = -INFINITY, run_s = 0.f;
    f4 a = (f4)0.f;

    #pragma unroll
    for (int batch = 0; batch < RPB / BATCH; ++batch) {
        int nb0 = n0 + batch * BATCH;
        f4 x[BATCH];
        #pragma unroll
        for (int r = 0; r < BATCH; ++r) {
            int n = nb0 + r;
            const float* src = (n < NPREV) ? (prev + (size_t)n * D) : inp;
            x[r] = nt_load4(src + 4 * tid);
        }
        float p[BATCH];
        #pragma unroll
        for (int r = 0; r < BATCH; ++r) {
            int n = nb0 + r;
            nt_store4(x[r], io + (size_t)n * D + 4 * tid);
            p[r] = x[r].x * kqv.x + x[r].y * kqv.y + x[r].z * kqv.z + x[r].w * kqv.w;
        }
        #pragma unroll
        for (int r = 0; r < BATCH; ++r) {
            float v = p[r];
            #pragma unroll
            for (int off = 32; off; off >>= 1) v += __shfl_down(v, off, 64);
            if (lane == 0) s_wred[wid * BATCH + r] = v;
        }
        __syncthreads();
        if (tid < BATCH) {
            float s = 0.f;
            #pragma unroll
            for (int w = 0; w < 16; ++w) s += s_wred[w * BATCH + tid];
            s_log[tid] = s;
        }
        __syncthreads();
        // online softmax update (every thread computes identically from LDS)
        float m_new = run_m;
        #pragma unroll
        for (int r = 0; r < BATCH; ++r) m_new = fmaxf(m_new, s_log[r]);
        float scale = __expf(run_m - m_new);   // first batch: exp(-inf)=0
        a *= scale; run_s *= scale;
        #pragma unroll
        for (int r = 0; r < BATCH; ++r) {
            float e = __expf(s_log[r] - m_new);
            run_s += e;
            a += e * x[r];
        }
        run_m = m_new;
        // no barrier needed: next batch's s_wred write precedes a syncthreads
        // before s_log is overwritten.
    }
    st4(a, ctxpart + (size_t)bid * D + 4 * tid);
    if (tid == 0) { ms[2 * bid] = run_m; ms[2 * bid + 1] = run_s; }
}

// ============ P4: combine 256 block partials -> normalized ctx ===============
static __device__ __forceinline__ void phase_combine(
        const float* __restrict__ ms, const float* __restrict__ ctxpart,
        float* __restrict__ ctx, int bid, int tid,
        float* s_ms /*512*/, f4* s_red /*1024 f4*/) {
    if (tid < 2 * NB) s_ms[tid] = ms[tid];
    __syncthreads();
    float M = -INFINITY;
    #pragma unroll 8
    for (int b = 0; b < NB; ++b) M = fmaxf(M, s_ms[2 * b]);
    float S = 0.f;
    #pragma unroll 8
    for (int b = 0; b < NB; ++b) S += s_ms[2 * b + 1] * __expf(s_ms[2 * b] - M);
    int c  = tid & 3;
    int j  = tid >> 2;                  // 0..255 partial index
    int c4 = bid * 4 + c;               // 256 blocks * 4 = 1024 f4 columns
    f4 v = __expf(s_ms[2 * j] - M) * ld4(ctxpart + (size_t)j * D + 4 * c4);
    s_red[tid] = v;
    __syncthreads();
    #pragma unroll
    for (int stride = 128; stride >= 1; stride >>= 1) {
        if (j < stride) s_red[tid] += s_red[tid + stride * 4];
        __syncthreads();
    }
    if (j == 0) st4(s_red[tid] * (1.f / S), ctx + 4 * c4);
}

// ============ cooperative mega-kernel ========================================
__global__ __launch_bounds__(NT, 4) void k_mega(
        const float* prev, const float* inp, const float* W_Q,
        const float* W_K, const float* W_V, float* out,
        float* q, float* kq, float* kqpart, float* ms,
        float* ctxpart, float* ctx) {
    cg::grid_group grid = cg::this_grid();
    __shared__ float smem[4608];        // 18 KiB: reused across phases
    int bid = blockIdx.x, tid = threadIdx.x;

    phase_matvec(W_Q, inp, nullptr, q, bid, tid);
    grid.sync();
    phase_colpart(W_K, q, kqpart, bid, tid, smem);
    grid.sync();
    phase_colreduce(kqpart, kq, bid, tid);
    grid.sync();
    phase_flash(prev, inp, kq, out + D, ms, ctxpart, bid, tid, smem, smem + 256);
    grid.sync();
    phase_combine(ms, ctxpart, ctx, bid, tid, smem + 4096, (f4*)smem);
    grid.sync();
    phase_matvec(W_V, ctx, inp, out, bid, tid);
}

// ============ fallback: same phases as separate kernels ======================
__global__ __launch_bounds__(NT, 4) void k_p1(const float* W, const float* v,
                                              const float* resid, float* out) {
    phase_matvec(W, v, resid, out, blockIdx.x, threadIdx.x);
}
__global__ __launch_bounds__(NT, 4) void k_p2a(const float* W, const float* q,
                                               float* kqpart) {
    __shared__ float s_q[16];
    phase_colpart(W, q, kqpart, blockIdx.x, threadIdx.x, s_q);
}
__global__ __launch_bounds__(NT, 4) void k_p2b(const float* kqpart, float* kq) {
    phase_colreduce(kqpart, kq, blockIdx.x, threadIdx.x);
}
__global__ __launch_bounds__(NT, 4) void k_p3(const float* prev, const float* inp,
                                              const float* kq, float* io,
                                              float* ms, float* ctxpart) {
    __shared__ float smem[272];
    phase_flash(prev, inp, kq, io, ms, ctxpart, blockIdx.x, threadIdx.x,
                smem, smem + 256);
}
__global__ __launch_bounds__(NT, 4) void k_p4(const float* ms, const float* ctxpart,
                                              float* ctx) {
    __shared__ float smem[4608];
    phase_combine(ms, ctxpart, ctx, blockIdx.x, threadIdx.x,
                  smem + 4096, (f4*)smem);
}

extern "C" void kernel_launch(void* const* d_in, const int* in_sizes, int n_in,
                              void* d_out, int out_size, void* d_ws, size_t ws_size,
                              hipStream_t stream) {
    const float* prev = (const float*)d_in[0];   // (8191, 4096)
    const float* inp  = (const float*)d_in[1];   // (4096,)
    const float* W_Q  = (const float*)d_in[2];
    const float* W_K  = (const float*)d_in[3];
    const float* W_V  = (const float*)d_in[4];
    float* out = (float*)d_out;                  // [0:4096]=output, [4096:]=inputs
    float* ws  = (float*)d_ws;

    // ws layout: q D | kq D | kqpart NB*D | ms 2*NB | ctxpart NB*D | ctx D
    float* q       = ws;
    float* kq      = q + D;
    float* kqpart  = kq + D;
    float* ms      = kqpart + (size_t)NB * D;
    float* ctxpart = ms + 2 * NB;
    float* ctx     = ctxpart + (size_t)NB * D;

    const float* prev_a = prev; const float* inp_a = inp;
    const float* wq_a = W_Q; const float* wk_a = W_K; const float* wv_a = W_V;
    float* out_a = out;
    void* args[] = { (void*)&prev_a, (void*)&inp_a, (void*)&wq_a, (void*)&wk_a,
                     (void*)&wv_a, (void*)&out_a, (void*)&q, (void*)&kq,
                     (void*)&kqpart, (void*)&ms, (void*)&ctxpart, (void*)&ctx };

    hipError_t err = hipLaunchCooperativeKernel(
        (const void*)k_mega, dim3(NB), dim3(NT), args, 0, stream);

    if (err != hipSuccess) {
        // fallback: same phases, separate launches (kernel boundary = sync)
        k_p1<<<NB, NT, 0, stream>>>(W_Q, inp, nullptr, q);
        k_p2a<<<NB, NT, 0, stream>>>(W_K, q, kqpart);
        k_p2b<<<NB, NT, 0, stream>>>(kqpart, kq);
        k_p3<<<NB, NT, 0, stream>>>(prev, inp, kq, out + D, ms, ctxpart);
        k_p4<<<NB, NT, 0, stream>>>(ms, ctxpart, ctx);
        k_p1<<<NB, NT, 0, stream>>>(W_V, ctx, inp, out);
    }
}

// Round 7
// 121.294 us; speedup vs baseline: 2.7056x; 2.7056x over previous
//
#include <hip/hip_runtime.h>
#include <math.h>

#define D      4096
#define NPREV  8191
#define NROWS  8192

typedef float f4 __attribute__((ext_vector_type(4)));

static __device__ __forceinline__ f4 nt_load4(const float* p) {
    return __builtin_nontemporal_load(reinterpret_cast<const f4*>(p));
}
static __device__ __forceinline__ void nt_store4(f4 v, float* p) {
    __builtin_nontemporal_store(v, reinterpret_cast<f4*>(p));
}
static __device__ __forceinline__ f4 ld4(const float* p) {
    return *reinterpret_cast<const f4*>(p);
}
static __device__ __forceinline__ void st4(f4 v, float* p) {
    *reinterpret_cast<f4*>(p) = v;
}

// ---- K1/K7: out[row] = dot(W[row,:], v) (+resid). 1024 blocks x 256 ---------
template<bool RESIDUAL>
__global__ void k_matvec_rows(const float* __restrict__ W, const float* __restrict__ v,
                              const float* __restrict__ resid, float* __restrict__ out) {
    int row  = blockIdx.x * 4 + (threadIdx.x >> 6);
    int lane = threadIdx.x & 63;
    const float* Wrow = W + (size_t)row * D;
    float acc = 0.f;
    #pragma unroll
    for (int i = 0; i < 16; ++i) {
        int c = lane + i * 64;
        f4 w = nt_load4(Wrow + 4 * c);
        f4 x = ld4(v + 4 * c);
        acc += w.x * x.x + w.y * x.y + w.z * x.z + w.w * x.w;
    }
    #pragma unroll
    for (int off = 32; off; off >>= 1) acc += __shfl_down(acc, off, 64);
    if (lane == 0) out[row] = RESIDUAL ? (acc + resid[row]) : acc;
}

// ---- K2: part[c][d] = sum_{m in chunk c} q[m]*W[m][d]. grid(4,64) x 256 -----
#define NCH 64
__global__ void k_colvec_partial(const float* __restrict__ W, const float* __restrict__ q,
                                 float* __restrict__ part) {
    int d4 = blockIdx.x * 256 + threadIdx.x;     // 0..1023 f4 columns
    int m0 = blockIdx.y * (D / NCH);             // 64 rows per chunk
    f4 acc = (f4)0.f;
    #pragma unroll 4
    for (int r = 0; r < D / NCH; ++r) {
        float qm = q[m0 + r];
        acc += qm * nt_load4(W + (size_t)(m0 + r) * D + 4 * d4);
    }
    st4(acc, part + (size_t)blockIdx.y * D + 4 * d4);
}

// ---- K3: kq[d] = sum_c part[c][d]. 64 blocks x 256; 256B-coalesced reads ----
__global__ void k_kq_reduce(const float* __restrict__ part, float* __restrict__ kq) {
    __shared__ float s[4][64];
    int b = blockIdx.x;
    int cg = threadIdx.x >> 6, l = threadIdx.x & 63;
    float acc = 0.f;
    #pragma unroll
    for (int i = 0; i < NCH / 4; ++i)
        acc += part[(size_t)(cg * (NCH / 4) + i) * D + b * 64 + l];
    s[cg][l] = acc;
    __syncthreads();
    if (cg == 0) kq[b * 64 + l] = s[0][l] + s[1][l] + s[2][l] + s[3][l];
}

// ---- K4: register-resident flash. FB=512 x 1024 thr, FR=16 rows/block ------
#define FB   512
#define FR   (NROWS / FB)   // 16
__global__ __launch_bounds__(1024, 4) void k_flash(
        const float* __restrict__ prev, const float* __restrict__ inp,
        const float* __restrict__ kq, float* __restrict__ io,
        float* __restrict__ ms, float* __restrict__ ctxpart) {
    __shared__ float s_wred[16][FR];
    __shared__ float s_log[FR];
    const int n0 = blockIdx.x * FR;
    const int t = threadIdx.x;
    const int wid = t >> 6, lane = t & 63;
    const f4 kqv = ld4(kq + 4 * t);

    f4 x[FR];
    #pragma unroll
    for (int r = 0; r < FR; ++r) {
        int n = n0 + r;
        const float* src = (n < NPREV) ? (prev + (size_t)n * D) : inp;
        x[r] = nt_load4(src + 4 * t);
    }
    float p[FR];
    #pragma unroll
    for (int r = 0; r < FR; ++r) {
        int n = n0 + r;
        nt_store4(x[r], io + (size_t)n * D + 4 * t);
        p[r] = x[r].x * kqv.x + x[r].y * kqv.y + x[r].z * kqv.z + x[r].w * kqv.w;
    }
    #pragma unroll
    for (int r = 0; r < FR; ++r) {
        float v = p[r];
        #pragma unroll
        for (int off = 32; off; off >>= 1) v += __shfl_down(v, off, 64);
        if (lane == 0) s_wred[wid][r] = v;
    }
    __syncthreads();
    if (t < FR) {
        float s = 0.f;
        #pragma unroll
        for (int w = 0; w < 16; ++w) s += s_wred[w][t];
        s_log[t] = s;
    }
    __syncthreads();
    float m_b = -INFINITY;
    #pragma unroll
    for (int r = 0; r < FR; ++r) m_b = fmaxf(m_b, s_log[r]);
    float e[FR], s_b = 0.f;
    #pragma unroll
    for (int r = 0; r < FR; ++r) { e[r] = __expf(s_log[r] - m_b); s_b += e[r]; }
    f4 a = (f4)0.f;
    #pragma unroll
    for (int r = 0; r < FR; ++r) a += e[r] * x[r];
    st4(a, ctxpart + (size_t)blockIdx.x * D + 4 * t);
    if (t == 0) { ms[2 * blockIdx.x] = m_b; ms[2 * blockIdx.x + 1] = s_b; }
}

// ---- K5: combine level 1 — 32 groups of 16 partials. grid(4,32) x 256 -------
#define NGRP 32
#define GSZ  (FB / NGRP)    // 16
__global__ void k_combine1(const float* __restrict__ ms, const float* __restrict__ ctxpart,
                           float* __restrict__ ctx2, float* __restrict__ msg) {
    __shared__ float sm[2 * GSZ];
    int t = threadIdx.x, g = blockIdx.y;
    if (t < 2 * GSZ) sm[t] = ms[2 * GSZ * g + t];
    __syncthreads();
    float Mg = -INFINITY;
    #pragma unroll
    for (int i = 0; i < GSZ; ++i) Mg = fmaxf(Mg, sm[2 * i]);
    float Sg = 0.f;
    #pragma unroll
    for (int i = 0; i < GSZ; ++i) Sg += sm[2 * i + 1] * __expf(sm[2 * i] - Mg);
    int d4 = blockIdx.x * 256 + t;
    f4 a = (f4)0.f;
    #pragma unroll
    for (int i = 0; i < GSZ; ++i) {
        int b = GSZ * g + i;
        a += __expf(sm[2 * i] - Mg) * ld4(ctxpart + (size_t)b * D + 4 * d4);
    }
    st4(a, ctx2 + (size_t)g * D + 4 * d4);
    if (blockIdx.x == 0 && t == 0) { msg[2 * g] = Mg; msg[2 * g + 1] = Sg; }
}

// ---- K6: combine level 2 — merge 32 groups, normalize. grid(4) x 256 --------
__global__ void k_combine2(const float* __restrict__ msg, const float* __restrict__ ctx2,
                           float* __restrict__ ctx) {
    __shared__ float sm[2 * NGRP];
    int t = threadIdx.x;
    if (t < 2 * NGRP) sm[t] = msg[t];
    __syncthreads();
    float M = -INFINITY;
    #pragma unroll
    for (int g = 0; g < NGRP; ++g) M = fmaxf(M, sm[2 * g]);
    float S = 0.f;
    #pragma unroll
    for (int g = 0; g < NGRP; ++g) S += sm[2 * g + 1] * __expf(sm[2 * g] - M);
    int d4 = blockIdx.x * 256 + t;
    f4 a = (f4)0.f;
    #pragma unroll
    for (int g = 0; g < NGRP; ++g)
        a += __expf(sm[2 * g] - M) * ld4(ctx2 + (size_t)g * D + 4 * d4);
    st4(a * (1.f / S), ctx + 4 * d4);
}

extern "C" void kernel_launch(void* const* d_in, const int* in_sizes, int n_in,
                              void* d_out, int out_size, void* d_ws, size_t ws_size,
                              hipStream_t stream) {
    const float* prev = (const float*)d_in[0];   // (8191, 4096)
    const float* inp  = (const float*)d_in[1];   // (4096,)
    const float* W_Q  = (const float*)d_in[2];
    const float* W_K  = (const float*)d_in[3];
    const float* W_V  = (const float*)d_in[4];
    float* out = (float*)d_out;                  // [0:4096]=output, [4096:]=inputs
    float* io  = out + D;
    float* ws  = (float*)d_ws;

    // ws: q D | kq D | part NCH*D | ms 2*FB | ctxpart FB*D | ctx2 NGRP*D |
    //     msg 2*NGRP | ctx D   (~9.9 MB; R2-R5 proved ws >= 10.7 MB)
    float* q       = ws;
    float* kq      = q + D;
    float* part    = kq + D;
    float* ms      = part + (size_t)NCH * D;
    float* ctxpart = ms + 2 * FB;
    float* ctx2    = ctxpart + (size_t)FB * D;
    float* msg     = ctx2 + (size_t)NGRP * D;
    float* ctx     = msg + 2 * NGRP;

    k_matvec_rows<false><<<1024, 256, 0, stream>>>(W_Q, inp, nullptr, q);
    k_colvec_partial<<<dim3(4, NCH), 256, 0, stream>>>(W_K, q, part);
    k_kq_reduce<<<64, 256, 0, stream>>>(part, kq);
    k_flash<<<FB, 1024, 0, stream>>>(prev, inp, kq, io, ms, ctxpart);
    k_combine1<<<dim3(4, NGRP), 256, 0, stream>>>(ms, ctxpart, ctx2, msg);
    k_combine2<<<4, 256, 0, stream>>>(msg, ctx2, ctx);
    k_matvec_rows<true><<<1024, 256, 0, stream>>>(W_V, ctx, inp, out);
}